// Round 7
// baseline (274.986 us; speedup 1.0000x reference)
//
#include <hip/hip_runtime.h>
#include <cstdint>
#include <cstddef>

// Problem constants
#define DMODEL 1024
#define HEADS  16
#define DHEAD  64
#define BATCH  4
#define SEQ    2048
#define ROWS   (BATCH * SEQ)          // 8192
#define INV_DSCALE 0.3535533905932738f // 1 / 64^(1/4)

typedef float  f32x4  __attribute__((ext_vector_type(4)));
typedef __bf16 bf16x8 __attribute__((ext_vector_type(8)));
typedef unsigned short u16x8 __attribute__((ext_vector_type(8)));

__device__ __forceinline__ unsigned short f2bf(float x) {
    union { float f; unsigned u; } c; c.f = x;
    unsigned u = c.u;
    return (unsigned short)((u + 0x7fffu + ((u >> 16) & 1u)) >> 16);
}

// Pack two f32 -> packed 2x bf16 (RNE).
__device__ __forceinline__ unsigned cvt_pk_bf16(float a, float b) {
#if __has_builtin(__builtin_amdgcn_cvt_pk_bf16_f32)
    typedef __bf16 bf16x2_t __attribute__((ext_vector_type(2)));
    union { bf16x2_t v; unsigned u; } c;
    c.v = __builtin_amdgcn_cvt_pk_bf16_f32(a, b);
    return c.u;
#else
    return (unsigned)f2bf(a) | ((unsigned)f2bf(b) << 16);
#endif
}

__device__ __forceinline__ void load_g2l16(const unsigned short* g, unsigned short* l) {
    __builtin_amdgcn_global_load_lds(
        (const __attribute__((address_space(1))) unsigned int*)g,
        (__attribute__((address_space(3))) unsigned int*)l,
        16 /*bytes*/, 0 /*offset*/, 0 /*aux*/);
}

// Fused 64-wide head-group softmax over a wave's 4 j-frags (one head).
__device__ __forceinline__ void softmax4(float v[4]) {
    #pragma unroll
    for (int j = 0; j < 4; ++j) v[j] *= INV_DSCALE;
    float m = fmaxf(fmaxf(v[0], v[1]), fmaxf(v[2], v[3]));
    #pragma unroll
    for (int off = 8; off; off >>= 1) m = fmaxf(m, __shfl_xor(m, off, 16));
    float s = 0.f;
    #pragma unroll
    for (int j = 0; j < 4; ++j) { v[j] = __expf(v[j] - m); s += v[j]; }
    #pragma unroll
    for (int off = 8; off; off >>= 1) s += __shfl_xor(s, off, 16);
    float inv = 1.0f / s;
    #pragma unroll
    for (int j = 0; j < 4; ++j) v[j] *= inv;
}

// ---------------------------------------------------------------------------
// Weight prep: blocks [0,768) pack Wq/Wk/Wv -> [n=h*64+d][k=m] bf16;
// blocks [768,1792) straight-cast Wo.
__global__ __launch_bounds__(256) void prep_w(const float* __restrict__ W0,
                                              const float* __restrict__ W1,
                                              const float* __restrict__ W2,
                                              const float* __restrict__ Wo,
                                              unsigned short* __restrict__ T0,
                                              unsigned short* __restrict__ T1,
                                              unsigned short* __restrict__ T2,
                                              unsigned short* __restrict__ To) {
    __shared__ float tile[64][68];
    int blk = blockIdx.x;
    int t = threadIdx.x;
    if (blk < 768) {
        int w = blk >> 8, h = (blk >> 4) & 15, mb = blk & 15;
        const float* W = w == 0 ? W0 : (w == 1 ? W1 : W2);
        unsigned short* T = w == 0 ? T0 : (w == 1 ? T1 : T2);
        #pragma unroll
        for (int i = 0; i < 4; ++i) {
            int f = t + 256 * i;
            int m = f >> 4, dg = (f & 15) * 4;
            *(float4*)&tile[m][dg] = *(const float4*)&W[((size_t)(h * 16 + mb) * 64 + m) * 64 + dg];
        }
        __syncthreads();
        #pragma unroll
        for (int i = 0; i < 2; ++i) {
            int f = t + 256 * i;
            int d = f >> 3, mg = f & 7;
            ushort4 a, b;
            a.x = f2bf(tile[mg * 8 + 0][d]); a.y = f2bf(tile[mg * 8 + 1][d]);
            a.z = f2bf(tile[mg * 8 + 2][d]); a.w = f2bf(tile[mg * 8 + 3][d]);
            b.x = f2bf(tile[mg * 8 + 4][d]); b.y = f2bf(tile[mg * 8 + 5][d]);
            b.z = f2bf(tile[mg * 8 + 6][d]); b.w = f2bf(tile[mg * 8 + 7][d]);
            unsigned short* dst = T + (size_t)(h * 64 + d) * DMODEL + mb * 64 + mg * 8;
            *(ushort4*)dst = a; *(ushort4*)(dst + 4) = b;
        }
    } else {
        int i = (blk - 768) * 256 + t;
        float4 v = ((const float4*)Wo)[i];
        ushort4 o;
        o.x = f2bf(v.x); o.y = f2bf(v.y); o.z = f2bf(v.z); o.w = f2bf(v.w);
        ((ushort4*)To)[i] = o;
    }
}

// ---------------------------------------------------------------------------
// Projections, m97-shaped: 128x128 block tile, BK=32, 4 waves each 64x64 via
// 4x4 of 16x16x32 MFMA. A fp32 converted to bf16 during LDS staging; B via
// global_load_lds. XOR swizzle in the 4-group domain: LDS slot (row, s) holds
// global k-group s ^ (row&3).
// z=0: Q -> softmax -> Qb[row][1024]. z=1: K -> softmax -> Kt[bh][d][s]
// (LDS transpose). z=2: V -> Vt[bh][e][s].
__global__ __launch_bounds__(256, 3) void proj3(const float* __restrict__ xq,
                                                const float* __restrict__ xk,
                                                const float* __restrict__ xv,
                                                const unsigned short* __restrict__ wq,
                                                const unsigned short* __restrict__ wk,
                                                const unsigned short* __restrict__ wv,
                                                unsigned short* __restrict__ Qb,
                                                unsigned short* __restrict__ Kt,
                                                unsigned short* __restrict__ Vt) {
    __shared__ unsigned short smem[17408];      // 34.8 KB: staging (16 KB) U Ct
    unsigned short* ldsA = smem;                // 128*32 u16 = 8 KB
    unsigned short* ldsB = smem + 4096;         // 128*32 u16 = 8 KB

    int z = blockIdx.y;
    const float* A = z == 0 ? xq : (z == 1 ? xk : xv);
    const unsigned short* B = z == 0 ? wq : (z == 1 ? wk : wv);

    // XCD-aware decode: 512 blocks = 64 m x 8 n; flat%8 = XCD slot, each XCD
    // owns an 8m x 8n patch (1024 contiguous A rows -> its L2).
    int flat = blockIdx.x;
    int xcd = flat & 7, idx = flat >> 3;
    int bm0 = (xcd * 8 + (idx >> 3)) * 128;
    int bn0 = (idx & 7) * 128;

    const int t    = threadIdx.x;
    const int lane = t & 63;
    const int wave = t >> 6;
    const int wm   = (wave & 1) * 64;
    const int wn   = (wave >> 1) * 64;
    const int fr   = lane & 15;
    const int quad = lane >> 4;

    f32x4 acc[4][4] = {};

    // staging addressing: f = t + 256*i (i<2): row = f>>2, slot = f&3,
    // global k-group = slot ^ (row&3). LDS dest linear in f (g2l constraint).
    unsigned offA[2], offB[2];
    #pragma unroll
    for (int i = 0; i < 2; ++i) {
        int f = t + 256 * i, row = f >> 2, kg = (f & 3) ^ (row & 3);
        offA[i] = (unsigned)(bm0 + row) * DMODEL + kg * 8;
        offB[i] = (unsigned)(bn0 + row) * DMODEL + kg * 8;
    }

    for (int k0 = 0; k0 < DMODEL; k0 += 32) {
        #pragma unroll
        for (int i = 0; i < 2; ++i) {
            const float* src = A + offA[i] + k0;
            float4 lo = *(const float4*)src;
            float4 hi = *(const float4*)(src + 4);
            uint4 pk;
            pk.x = cvt_pk_bf16(lo.x, lo.y);
            pk.y = cvt_pk_bf16(lo.z, lo.w);
            pk.z = cvt_pk_bf16(hi.x, hi.y);
            pk.w = cvt_pk_bf16(hi.z, hi.w);
            *(uint4*)&ldsA[(t + 256 * i) * 8] = pk;
        }
        #pragma unroll
        for (int i = 0; i < 2; ++i)
            load_g2l16(B + offB[i] + k0, &ldsB[(t + 256 * i) * 8]);
        asm volatile("s_waitcnt vmcnt(0)" ::: "memory");
        __syncthreads();

        bf16x8 af[4], bfr[4];
        #pragma unroll
        for (int i = 0; i < 4; ++i) {
            int row = wm + i * 16 + fr;
            int s = quad ^ (row & 3);
            af[i] = *reinterpret_cast<const bf16x8*>(&ldsA[row * 32 + s * 8]);
        }
        #pragma unroll
        for (int j = 0; j < 4; ++j) {
            int row = wn + j * 16 + fr;
            int s = quad ^ (row & 3);
            bfr[j] = *reinterpret_cast<const bf16x8*>(&ldsB[row * 32 + s * 8]);
        }
        #pragma unroll
        for (int i = 0; i < 4; ++i)
            #pragma unroll
            for (int j = 0; j < 4; ++j)
                acc[i][j] = __builtin_amdgcn_mfma_f32_16x16x32_bf16(af[i], bfr[j], acc[i][j], 0, 0, 0);

        __syncthreads();
    }

    // epilogue. C/D layout: col = fr, row = quad*4 + r.
    if (z == 0) {
        #pragma unroll
        for (int i = 0; i < 4; ++i)
            #pragma unroll
            for (int r = 0; r < 4; ++r) {
                float v[4];
                #pragma unroll
                for (int j = 0; j < 4; ++j) v[j] = acc[i][j][r];
                softmax4(v);
                int rr = bm0 + wm + i * 16 + quad * 4 + r;
                size_t base = (size_t)rr * DMODEL + bn0 + wn + fr;
                #pragma unroll
                for (int j = 0; j < 4; ++j) Qb[base + j * 16] = f2bf(v[j]);
            }
    } else {
        // transpose via LDS: Ct[col 0..127][s_local 0..127], pitch 136.
        unsigned short* Ct = smem;              // 128*136 u16 = 34816 B
        #pragma unroll
        for (int i = 0; i < 4; ++i)
            #pragma unroll
            for (int r = 0; r < 4; ++r) {
                float v[4];
                #pragma unroll
                for (int j = 0; j < 4; ++j) v[j] = acc[i][j][r];
                if (z == 1) softmax4(v);
                int rr = wm + i * 16 + quad * 4 + r;          // s_local
                #pragma unroll
                for (int j = 0; j < 4; ++j) {
                    int cc = wn + j * 16 + fr;                // col
                    Ct[cc * 136 + rr] = f2bf(v[j]);
                }
            }
        __syncthreads();
        // coalesced copy out: col c = t>>1, s-half (t&1)*64 (64 u16 = 8 uint4)
        unsigned short* T = (z == 1) ? Kt : Vt;
        int c = t >> 1, sh = (t & 1) * 64;
        int col = bn0 + c, h = col >> 6, d = col & 63;
        int b = bm0 >> 11, s0 = bm0 & 2047;
        unsigned short* dst = T + (((size_t)(b * 16 + h) * 64 + d) << 11) + s0 + sh;
        const unsigned short* src = &Ct[c * 136 + sh];
        #pragma unroll
        for (int k = 0; k < 8; ++k)
            *(uint4*)(dst + k * 8) = *(const uint4*)(src + k * 8);
    }
}

// ---------------------------------------------------------------------------
// R6-proven 64x128 GEMM tile for the output projection: BK=64, 4 waves each
// 32x64 (2x4 of 16x16x32). XOR swizzle in the 8-group domain.
__device__ __forceinline__ void gemm_tile_out(const unsigned short* __restrict__ Ap,
                                              const unsigned short* __restrict__ Bp,
                                              int K, int bm0, int bn0,
                                              unsigned short* smem, f32x4 acc[2][4]) {
    unsigned short* ldsA = smem;            // 64*64 u16 = 8 KB
    unsigned short* ldsB = smem + 4096;     // 128*64 u16 = 16 KB

    const int t    = threadIdx.x;
    const int lane = t & 63;
    const int wave = t >> 6;
    const int wm   = (wave & 1) * 32;
    const int wn   = (wave >> 1) * 64;
    const int fr   = lane & 15;
    const int quad = lane >> 4;

    unsigned offA[2], offB[4];
    #pragma unroll
    for (int i = 0; i < 2; ++i) {
        int f = t + 256 * i, row = f >> 3, kg = (f & 7) ^ (row & 7);
        offA[i] = (unsigned)(bm0 + row) * K + kg * 8;
    }
    #pragma unroll
    for (int i = 0; i < 4; ++i) {
        int f = t + 256 * i, row = f >> 3, kg = (f & 7) ^ (row & 7);
        offB[i] = (unsigned)(bn0 + row) * K + kg * 8;
    }

    for (int k0 = 0; k0 < K; k0 += 64) {
        #pragma unroll
        for (int i = 0; i < 2; ++i)
            load_g2l16(Ap + offA[i] + k0, &ldsA[(t + 256 * i) * 8]);
        #pragma unroll
        for (int i = 0; i < 4; ++i)
            load_g2l16(Bp + offB[i] + k0, &ldsB[(t + 256 * i) * 8]);
        asm volatile("s_waitcnt vmcnt(0)" ::: "memory");
        __syncthreads();

        bf16x8 af[2][2], bfr[4][2];
        #pragma unroll
        for (int i = 0; i < 2; ++i) {
            int row = wm + i * 16 + fr;
            #pragma unroll
            for (int kh = 0; kh < 2; ++kh) {
                int s = (kh * 4 + quad) ^ (row & 7);
                af[i][kh] = *reinterpret_cast<const bf16x8*>(&ldsA[row * 64 + s * 8]);
            }
        }
        #pragma unroll
        for (int j = 0; j < 4; ++j) {
            int row = wn + j * 16 + fr;
            #pragma unroll
            for (int kh = 0; kh < 2; ++kh) {
                int s = (kh * 4 + quad) ^ (row & 7);
                bfr[j][kh] = *reinterpret_cast<const bf16x8*>(&ldsB[row * 64 + s * 8]);
            }
        }
        #pragma unroll
        for (int kh = 0; kh < 2; ++kh)
            #pragma unroll
            for (int i = 0; i < 2; ++i)
                #pragma unroll
                for (int j = 0; j < 4; ++j)
                    acc[i][j] = __builtin_amdgcn_mfma_f32_16x16x32_bf16(af[i][kh], bfr[j][kh], acc[i][j], 0, 0, 0);

        __syncthreads();
    }
}

// XCD-aware decode for 1024 blocks (128 m x 8 n of 64x128 tiles).
__device__ __forceinline__ void decode_blk64(int flat, int& bm0, int& bn0) {
    int xcd = flat & 7, idx = flat >> 3;
    bm0 = (xcd * 16 + (idx >> 3)) * 64;
    bn0 = (idx & 7) * 128;
}

// out = R (bf16 [8192,1024] flat) @ Wo^T -> fp32
__global__ __launch_bounds__(256, 4) void gemm_out(const unsigned short* __restrict__ R,
                                                   const unsigned short* __restrict__ Wo,
                                                   float* __restrict__ out) {
    __shared__ unsigned short smem[12288];
    int bm0, bn0;
    decode_blk64(blockIdx.x, bm0, bn0);
    f32x4 acc[2][4] = {};
    gemm_tile_out(R, Wo, DMODEL, bm0, bn0, smem, acc);

    const int t = threadIdx.x, lane = t & 63, wave = t >> 6;
    const int wm = (wave & 1) * 32, wn = (wave >> 1) * 64;
    const int fr = lane & 15, quad = lane >> 4;
    #pragma unroll
    for (int i = 0; i < 2; ++i)
        #pragma unroll
        for (int r = 0; r < 4; ++r) {
            int rr = bm0 + wm + i * 16 + quad * 4 + r;
            size_t base = (size_t)rr * DMODEL + bn0 + wn + fr;
            #pragma unroll
            for (int j = 0; j < 4; ++j) out[base + j * 16] = acc[i][j][r];
        }
}

// ---------------------------------------------------------------------------
// P[chunk][bh][e][d] = sum over 256 s of Vt[bh,e,s] * Kt[bh,d,s]  (MFMA).
// grid: bh*8 + chunk (512 blocks).
__global__ __launch_bounds__(256) void kv_mfma(const unsigned short* __restrict__ Vt,
                                               const unsigned short* __restrict__ Kt,
                                               float* __restrict__ P) {
    __shared__ unsigned short ldsV[64 * 64];    // 8 KB
    __shared__ unsigned short ldsK[64 * 64];    // 8 KB
    int bh = blockIdx.x >> 3, chunk = blockIdx.x & 7;
    int t = threadIdx.x, lane = t & 63, wave = t >> 6;
    int fr = lane & 15, quad = lane >> 4;

    unsigned offV[2], offK[2];
    #pragma unroll
    for (int i = 0; i < 2; ++i) {
        int f = t + 256 * i, row = f >> 3, kg = (f & 7) ^ (row & 7);
        unsigned o = ((unsigned)(bh * 64 + row) << 11) + chunk * 256 + kg * 8;
        offV[i] = o; offK[i] = o;
    }

    f32x4 acc[4] = {};
    for (int k0 = 0; k0 < 256; k0 += 64) {
        #pragma unroll
        for (int i = 0; i < 2; ++i)
            load_g2l16(Vt + offV[i] + k0, &ldsV[(t + 256 * i) * 8]);
        #pragma unroll
        for (int i = 0; i < 2; ++i)
            load_g2l16(Kt + offK[i] + k0, &ldsK[(t + 256 * i) * 8]);
        asm volatile("s_waitcnt vmcnt(0)" ::: "memory");
        __syncthreads();

        #pragma unroll
        for (int kh = 0; kh < 2; ++kh) {
            int rowA = wave * 16 + fr;
            int sA = (kh * 4 + quad) ^ (rowA & 7);
            bf16x8 av = *reinterpret_cast<const bf16x8*>(&ldsV[rowA * 64 + sA * 8]);
            #pragma unroll
            for (int j = 0; j < 4; ++j) {
                int rowB = j * 16 + fr;
                int sB = (kh * 4 + quad) ^ (rowB & 7);
                bf16x8 bv = *reinterpret_cast<const bf16x8*>(&ldsK[rowB * 64 + sB * 8]);
                acc[j] = __builtin_amdgcn_mfma_f32_16x16x32_bf16(av, bv, acc[j], 0, 0, 0);
            }
        }
        __syncthreads();
    }
    float* Pp = P + ((size_t)chunk * 64 + bh) * 4096;
    #pragma unroll
    for (int j = 0; j < 4; ++j)
        #pragma unroll
        for (int r = 0; r < 4; ++r)
            Pp[(wave * 16 + quad * 4 + r) * 64 + j * 16 + fr] = acc[j][r];
}

// At[idx] (bf16) = sum over 8 chunks of P[chunk][idx]
__global__ __launch_bounds__(256) void reduce_A(const float* __restrict__ P,
                                                unsigned short* __restrict__ At) {
    int idx = blockIdx.x * 256 + threadIdx.x;   // 0 .. 262143
    float s = 0.f;
    #pragma unroll
    for (int c = 0; c < 8; ++c) s += P[(size_t)c * (64 * 4096) + idx];
    At[idx] = f2bf(s);
}

// ---------------------------------------------------------------------------
// R[bh][s][e] = sum_d Qs[b,s,h*64+d] * At[bh][e][d]  (MFMA, K=64).
// grid: bh*16 + sb (sb covers 128 s rows). Output bf16 flat [b,h,s,e].
__global__ __launch_bounds__(256, 4) void qs_mfma(const unsigned short* __restrict__ Qb,
                                                  const unsigned short* __restrict__ At,
                                                  unsigned short* __restrict__ R) {
    __shared__ unsigned short ldsQ[128 * 64];   // 16 KB
    __shared__ unsigned short ldsB[64 * 64];    // 8 KB
    int bh = blockIdx.x >> 4, sb = blockIdx.x & 15;
    int b = bh >> 4, h = bh & 15;
    int t = threadIdx.x, lane = t & 63, wave = t >> 6;
    int fr = lane & 15, quad = lane >> 4;
    int wm = wave * 32;

    #pragma unroll
    for (int i = 0; i < 4; ++i) {
        int f = t + 256 * i, row = f >> 3, kg = (f & 7) ^ (row & 7);
        const unsigned short* src = Qb + ((size_t)(b * SEQ + sb * 128 + row) << 10) + h * 64 + kg * 8;
        load_g2l16(src, &ldsQ[f * 8]);
    }
    #pragma unroll
    for (int i = 0; i < 2; ++i) {
        int f = t + 256 * i, row = f >> 3, kg = (f & 7) ^ (row & 7);
        load_g2l16(At + (unsigned)bh * 4096 + row * 64 + kg * 8, &ldsB[f * 8]);
    }
    asm volatile("s_waitcnt vmcnt(0)" ::: "memory");
    __syncthreads();

    f32x4 acc[2][4] = {};
    #pragma unroll
    for (int kh = 0; kh < 2; ++kh) {
        bf16x8 af[2], bfr[4];
        #pragma unroll
        for (int i = 0; i < 2; ++i) {
            int row = wm + i * 16 + fr;
            int s = (kh * 4 + quad) ^ (row & 7);
            af[i] = *reinterpret_cast<const bf16x8*>(&ldsQ[row * 64 + s * 8]);
        }
        #pragma unroll
        for (int j = 0; j < 4; ++j) {
            int row = j * 16 + fr;
            int s = (kh * 4 + quad) ^ (row & 7);
            bfr[j] = *reinterpret_cast<const bf16x8*>(&ldsB[row * 64 + s * 8]);
        }
        #pragma unroll
        for (int i = 0; i < 2; ++i)
            #pragma unroll
            for (int j = 0; j < 4; ++j)
                acc[i][j] = __builtin_amdgcn_mfma_f32_16x16x32_bf16(af[i], bfr[j], acc[i][j], 0, 0, 0);
    }

    #pragma unroll
    for (int i = 0; i < 2; ++i)
        #pragma unroll
        for (int r = 0; r < 4; ++r) {
            int rr = wm + i * 16 + quad * 4 + r;
            size_t base = ((size_t)bh << 17) + (size_t)(sb * 128 + rr) * 64;
            #pragma unroll
            for (int j = 0; j < 4; ++j)
                R[base + j * 16 + fr] = f2bf(acc[i][j][r]);
        }
}

// ---------------------------------------------------------------------------
extern "C" void kernel_launch(void* const* d_in, const int* in_sizes, int n_in,
                              void* d_out, int out_size, void* d_ws, size_t ws_size,
                              hipStream_t stream) {
    const float* xq = (const float*)d_in[0];
    const float* xk = (const float*)d_in[1];
    const float* xv = (const float*)d_in[2];
    const float* Wq = (const float*)d_in[3];
    const float* Wk = (const float*)d_in[4];
    const float* Wv = (const float*)d_in[5];
    const float* Wo = (const float*)d_in[6];
    float* out = (float*)d_out;
    char* ws = (char*)d_ws;

    const size_t MB = 1ull << 20;
    unsigned short* wq_t = (unsigned short*)(ws + 0 * MB);    // 2 MB each
    unsigned short* wk_t = (unsigned short*)(ws + 2 * MB);
    unsigned short* wv_t = (unsigned short*)(ws + 4 * MB);
    unsigned short* wo_b = (unsigned short*)(ws + 6 * MB);    // 2 MB
    unsigned short* Qb = (unsigned short*)(ws + 8 * MB);      // 16 MB
    unsigned short* Kt = (unsigned short*)(ws + 24 * MB);     // 16 MB [bh][d][s]
    unsigned short* Vt = (unsigned short*)(ws + 40 * MB);     // 16 MB [bh][e][s]
    unsigned short* At = (unsigned short*)(ws + 56 * MB);     // 0.5 MB [bh][e][d]
    unsigned short* R  = (unsigned short*)(ws + 57 * MB);     // 16 MB
    float* P = (float*)(ws + 73 * MB);                        // 8 MB

    // weights -> bf16
    prep_w<<<1792, 256, 0, stream>>>(Wq, Wk, Wv, Wo, wq_t, wk_t, wv_t, wo_b);

    // projections (m97-shaped 128x128/BK=32, fused cast + softmax + transpose)
    proj3<<<dim3(512, 3), 256, 0, stream>>>(xq, xk, xv, wq_t, wk_t, wv_t, Qb, Kt, Vt);

    // At = (softmax(K)^T V)^T per bh via MFMA, split-8 + deterministic reduce
    kv_mfma<<<BATCH * HEADS * 8, 256, 0, stream>>>(Vt, Kt, P);
    reduce_A<<<1024, 256, 0, stream>>>(P, At);

    // R = softmax(Q) A -> bf16, [b,h,s,e] flat (== reference view)
    qs_mfma<<<BATCH * HEADS * 16, 256, 0, stream>>>(Qb, At, R);

    // out = R @ Wo^T (fp32)
    gemm_out<<<1024, 256, 0, stream>>>(R, wo_b, out);
}